// Round 10
// baseline (148.353 us; speedup 1.0000x reference)
//
#include <hip/hip_runtime.h>
#include <math.h>

// Problem geometry (fixed by the reference)
#define BB 8
#define CC 256
#define HWSZ 36864            // floats per (b,c) slice
#define TPB 256
#define IT 36                 // float4 per thread per slice (36*256*4 = 36864 floats)
#define INTERNAL 16
#define NSLICE 2048
#define CHUNK_SLICES 1024     // 4 batches = 151 MB, fits 256 MB L3

typedef float f4 __attribute__((ext_vector_type(4)));

// ---- Pass A (per chunk): one block per slice, sum of squares ----
// Caching loads: deliberately leave the chunk resident in L3 for pass B.
__global__ __launch_bounds__(TPB) void se_sumsq_kernel(
    const float* __restrict__ in, float* __restrict__ sumsq, int base)
{
    const int bc = base + blockIdx.x;
    const f4* p = reinterpret_cast<const f4*>(in + (size_t)bc * HWSZ);

    float a0 = 0.f, a1 = 0.f, a2 = 0.f, a3 = 0.f;
    #pragma unroll
    for (int i = 0; i < IT; i += 4) {
        f4 v0 = p[threadIdx.x + (i + 0) * TPB];
        f4 v1 = p[threadIdx.x + (i + 1) * TPB];
        f4 v2 = p[threadIdx.x + (i + 2) * TPB];
        f4 v3 = p[threadIdx.x + (i + 3) * TPB];
        a0 += v0.x * v0.x + v0.y * v0.y + v0.z * v0.z + v0.w * v0.w;
        a1 += v1.x * v1.x + v1.y * v1.y + v1.z * v1.z + v1.w * v1.w;
        a2 += v2.x * v2.x + v2.y * v2.y + v2.z * v2.z + v2.w * v2.w;
        a3 += v3.x * v3.x + v3.y * v3.y + v3.z * v3.z + v3.w * v3.w;
    }
    float acc = (a0 + a1) + (a2 + a3);
    for (int off = 32; off > 0; off >>= 1)
        acc += __shfl_down(acc, off, 64);

    __shared__ float red[4];
    const int lane = threadIdx.x & 63, wave = threadIdx.x >> 6;
    if (lane == 0) red[wave] = acc;
    __syncthreads();
    if (threadIdx.x == 0)
        sumsq[bc] = red[0] + red[1] + red[2] + red[3];
}

// ---- Pass B (per chunk): inline gate MLP + streaming scale ----
// The chunk's input is L3-resident from pass A -> reads are L3 hits.
// nt-loads (last use of input) + nt-stores (output never read) keep the
// next chunk's L3 capacity clean.
__global__ __launch_bounds__(TPB) void se_scale_kernel(
    const float* __restrict__ in,
    const float* __restrict__ sumsq,   // [B*C]
    const float* __restrict__ w_down,  // [16, 256]
    const float* __restrict__ b_down,  // [16]
    const float* __restrict__ w_up,    // [256, 16]
    const float* __restrict__ b_up,    // [256]
    float* __restrict__ out, int base)
{
    const int s = base + (CHUNK_SLICES - 1) - blockIdx.x;
    const int b = s >> 8;
    const int c = s & 255;
    const int tid = threadIdx.x;

    __shared__ float xs[CC];
    __shared__ float hs[INTERNAL];
    __shared__ float gsh;

    // x[k] for all 256 channels of batch b
    {
        float g = sqrtf(sumsq[(b << 8) + tid]);
        xs[tid] = g / (g + 1e-6f);
    }
    __syncthreads();

    // h[j] = relu(b_down[j] + sum_k x[k]*w_down[j][k]); 16 threads per j
    {
        const int j = tid >> 4, l = tid & 15;
        const float* wr = w_down + j * CC;
        float a = 0.f;
        #pragma unroll
        for (int k = 0; k < CC / 16; ++k)
            a += xs[l + k * 16] * wr[l + k * 16];
        a += __shfl_down(a, 8, 16);
        a += __shfl_down(a, 4, 16);
        a += __shfl_down(a, 2, 16);
        a += __shfl_down(a, 1, 16);
        if (l == 0) hs[j] = fmaxf(a + b_down[j], 0.f);
    }
    __syncthreads();

    if (tid == 0) {
        float a = b_up[c];
        const float* wu = w_up + c * INTERNAL;
        #pragma unroll
        for (int j = 0; j < INTERNAL; ++j) a += hs[j] * wu[j];
        gsh = 1.f / (1.f + expf(-a));
    }
    __syncthreads();

    const float gv = gsh;
    const f4* pi = reinterpret_cast<const f4*>(in + (size_t)s * HWSZ);
    f4* po = reinterpret_cast<f4*>(out + (size_t)s * HWSZ);

    #pragma unroll
    for (int i = 0; i < IT; i += 4) {
        f4 v0 = __builtin_nontemporal_load(pi + tid + (i + 0) * TPB);
        f4 v1 = __builtin_nontemporal_load(pi + tid + (i + 1) * TPB);
        f4 v2 = __builtin_nontemporal_load(pi + tid + (i + 2) * TPB);
        f4 v3 = __builtin_nontemporal_load(pi + tid + (i + 3) * TPB);
        v0 *= gv; v1 *= gv; v2 *= gv; v3 *= gv;
        __builtin_nontemporal_store(v0, po + tid + (i + 0) * TPB);
        __builtin_nontemporal_store(v1, po + tid + (i + 1) * TPB);
        __builtin_nontemporal_store(v2, po + tid + (i + 2) * TPB);
        __builtin_nontemporal_store(v3, po + tid + (i + 3) * TPB);
    }
}

extern "C" void kernel_launch(void* const* d_in, const int* in_sizes, int n_in,
                              void* d_out, int out_size, void* d_ws, size_t ws_size,
                              hipStream_t stream) {
    const float* inputs = (const float*)d_in[0];   // [B, C, H, W]
    const float* w_down = (const float*)d_in[1];   // [16, 256]
    const float* b_down = (const float*)d_in[2];   // [16]
    const float* w_up   = (const float*)d_in[3];   // [256, 16]
    const float* b_up   = (const float*)d_in[4];   // [256]
    float* out   = (float*)d_out;
    float* sumsq = (float*)d_ws;                   // 2048 floats

    // Two L3-sized chunks: sumsq(chunk) then scale(chunk) while hot.
    for (int base = 0; base < NSLICE; base += CHUNK_SLICES) {
        se_sumsq_kernel<<<CHUNK_SLICES, TPB, 0, stream>>>(inputs, sumsq, base);
        se_scale_kernel<<<CHUNK_SLICES, TPB, 0, stream>>>(
            inputs, sumsq, w_down, b_down, w_up, b_up, out, base);
    }
}